// Round 15
// baseline (212.076 us; speedup 1.0000x reference)
//
#include <hip/hip_runtime.h>
#include <hip/hip_bf16.h>

#define BB 4096
#define SZ 32
#define DD 10000
#define DPAD 10240
#define NMOD 64
#define NROWS_M 128   // Mh(64) + Ml(64)
#define KSPLIT 4
#define KSEG 2560     // DPAD / KSPLIT
#define NWORDS 160    // DPAD/64 packed words per row
#define STEPS 40      // KSEG/64

// ws layout (bytes)
#define WS_BK_OFF     0u                 // 160*128*64*2 = 2.62 MB
#define WS_CPK_OFF    3145728u           // 160*64*8 = 80 KB
#define WS_PACK_OFF   4194304u           // 160*4096*8 = 5.24 MB
#define WS_CPART_OFF  10485760u          // 4*4096*128*4 = 8.39 MB  (end 18.9 MB)

typedef __attribute__((ext_vector_type(4))) float f32x4;
typedef __attribute__((ext_vector_type(8))) short short8;

static __device__ __forceinline__ ushort f2bf(float f) {
    unsigned u = __builtin_bit_cast(unsigned, f);
    unsigned r = (u + 0x7fffu + ((u >> 16) & 1u)) >> 16;   // RNE
    return (ushort)r;
}

// sign pipeline: 1 iff cosf(t+bk)*sinf(t) > 0, else 0 (covers ==0 -> -1).
static __device__ __forceinline__ int sign_pm(float t, float bk) {
    if (t == 0.0f) return 0;
    const double INV_PI_D = 0.31830988618379067153776752674503;
    float v = t + bk;
    long long n1 = (long long)floor((double)t * INV_PI_D);
    long long n2 = (long long)floor(fma((double)v, INV_PI_D, 0.5));
    return (int)(((n1 + n2) & 1LL) ^ 1LL);
}

// expand 8 packed bits (bit=1 -> +1.0bf16, 0 -> -1.0bf16) into short8
static __device__ __forceinline__ short8 expand8(unsigned b) {
    unsigned nb = ~b;
    unsigned r0 = 0x3F803F80u | ((nb & 1u) << 15) | ((nb & 2u) << 30);
    unsigned r1 = 0x3F803F80u | (((nb >> 2) & 1u) << 15) | (((nb >> 2) & 2u) << 30);
    unsigned r2 = 0x3F803F80u | (((nb >> 4) & 1u) << 15) | (((nb >> 4) & 2u) << 30);
    unsigned r3 = 0x3F803F80u | (((nb >> 6) & 1u) << 15) | (((nb >> 6) & 2u) << 30);
    uint4 u = make_uint4(r0, r1, r2, r3);
    return __builtin_bit_cast(short8, u);
}

// ---------------- K0: build Bk [160][128][64] bf16 (Mh, Ml) ---------------
__global__ __launch_bounds__(256) void k0_build_B(
        const float* __restrict__ M, ushort* __restrict__ Bk) {
    int k = blockIdx.x * 256 + threadIdx.x;   // 0..10239
    int row = blockIdx.y;                      // 0..127
    ushort u = 0;
    if (k < DD) {
        float m = M[(size_t)(row & 63) * DD + k];
        ushort mh = f2bf(m);
        if (row < 64) {
            u = mh;
        } else {
            float mhf = __builtin_bit_cast(float, (unsigned)mh << 16);
            u = f2bf(m - mhf);
        }
    }
    int step = k >> 6, kk = k & 63;
    Bk[((size_t)step * NROWS_M + row) * 64 + kk] = u;
}

// ---------------- K0b: pack cluster signs -> cpackT [160][64] u64 ---------
__global__ __launch_bounds__(256) void k0b_pack_c(
        const float* __restrict__ cluster, unsigned long long* __restrict__ cpackT) {
    const int tid = threadIdx.x;
    const int lane = tid & 63;
    const int wv = __builtin_amdgcn_readfirstlane(tid >> 6);
    const int w = blockIdx.x * 4 + wv;        // 0..159
    const int kb = w * 64;
    unsigned long long myw = 0;
    for (int m = 0; m < 64; ++m) {
        int k = kb + lane;
        int bit = (k < DD) ? (cluster[(size_t)m * DD + k] > 0.f ? 1 : 0) : 0;
        unsigned long long bal = __ballot(bit);
        if (lane == m) myw = bal;
    }
    cpackT[(size_t)w * 64 + lane] = myw;
}

// ---------------- K1: encode (T_G ordering), lane=row, no LDS -------------
// Per wave: 64 rows (lane=row, x in 32 VGPRs) x 64 cols (wave-uniform k:
// W/bias scalar loads). ballot -> column word; in-wave 64x64 bit transpose
// -> row words -> packedT + f32 enc expansion. Pad cols (k>=DD) get bit 0.
__global__ __launch_bounds__(256, 4) void k1_enc(
        const float* __restrict__ x, const float* __restrict__ W,
        const float* __restrict__ bias, float* __restrict__ enc_out,
        unsigned long long* __restrict__ packedT) {
    const int tid = threadIdx.x;
    const int lane = tid & 63;
    const int wv = __builtin_amdgcn_readfirstlane(tid >> 6);
    const int i0 = blockIdx.y * 64;
    const int colg = blockIdx.x * 4 + wv;     // 0..159
    const int kbase = colg * 64;

    float4 xr[8];
    {
        const float4* xp = reinterpret_cast<const float4*>(x + (size_t)(i0 + lane) * SZ);
        #pragma unroll
        for (int c = 0; c < 8; ++c) xr[c] = xp[c];
    }

    const int rem = DD - kbase;
    const int nvalid = rem <= 0 ? 0 : (rem < 64 ? rem : 64);

    unsigned long long colw = 0;
    if (nvalid > 0) {
        #pragma unroll 2
        for (int c = 0; c < 64; ++c) {
            int e = 0;
            if (c < nvalid) {                  // wave-uniform branch
                const int k = kbase + c;
                const float* wp = W + (size_t)k * SZ;   // uniform -> s_load
                float g0 = 0.f, g1 = 0.f, g2 = 0.f, g3 = 0.f;
                #pragma unroll
                for (int q = 0; q < 8; ++q) {
                    g0 = fmaf(wp[4 * q + 0], xr[q].x, g0);
                    g1 = fmaf(wp[4 * q + 1], xr[q].y, g1);
                    g2 = fmaf(wp[4 * q + 2], xr[q].z, g2);
                    g3 = fmaf(wp[4 * q + 3], xr[q].w, g3);
                }
                float t = (g0 + g1) + (g2 + g3);
                e = sign_pm(t, bias[k]);
            }
            unsigned long long bal = __ballot(e);
            if (lane == c) colw = bal;
        }
    }

    // in-wave 64x64 bit transpose: lane=col/bit=row  ->  lane=row/bit=col
    unsigned long long w64 = colw;
    {
        const unsigned long long MK[6] = {
            0x5555555555555555ull, 0x3333333333333333ull, 0x0F0F0F0F0F0F0F0Full,
            0x00FF00FF00FF00FFull, 0x0000FFFF0000FFFFull, 0x00000000FFFFFFFFull};
        #pragma unroll
        for (int j = 0; j < 6; ++j) {
            int s = 1 << j;
            unsigned long long m = MK[j];
            unsigned long long xo = __shfl_xor(w64, s, 64);
            if (lane & s) w64 = (w64 & ~m) | ((xo & ~m) >> s);
            else          w64 = (w64 & m) | ((xo & m) << s);
        }
    }

    // lane holds row word (row i0+lane, cols kbase..kbase+63)
    packedT[(size_t)colg * BB + i0 + lane] = w64;

    // expand to f32 enc (+-1) and store (valid cols only; nvalid % 4 == 0)
    float* ep = enc_out + (size_t)(i0 + lane) * DD + kbase;
    const int ng = nvalid >> 2;
    for (int g = 0; g < ng; ++g) {
        float4 f;
        f.x = ((w64 >> (4 * g + 0)) & 1ull) ? 1.f : -1.f;
        f.y = ((w64 >> (4 * g + 1)) & 1ull) ? 1.f : -1.f;
        f.z = ((w64 >> (4 * g + 2)) & 1ull) ? 1.f : -1.f;
        f.w = ((w64 >> (4 * g + 3)) & 1ull) ? 1.f : -1.f;
        reinterpret_cast<float4*>(ep)[g] = f;
    }
}

// ---------------- K2: fragment-direct MFMA GEMM, M-part only --------------
// grid (64 row-groups, 4 segs), 256 thr = 4 waves = 4 col-groups of 32.
__global__ __launch_bounds__(256, 2) void k2_gemm(
        const unsigned long long* __restrict__ packedT,  // [160][4096]
        const ushort* __restrict__ Bk,                   // [160][128][64]
        float* __restrict__ Cpart) {
    const int tid = threadIdx.x;
    const int wid = tid >> 6;       // col-group 0..3
    const int lane = tid & 63;
    const int fr = lane & 15;
    const int fg = lane >> 4;

    const int row0 = blockIdx.x * 64;
    const int seg = blockIdx.y;
    const int wcol = wid * 32;

    const unsigned long long* pA = packedT + (size_t)(seg * STEPS) * BB + row0 + fr;
    const ushort* pB = Bk + ((size_t)(seg * STEPS) * NROWS_M + wcol + fr) * 64 + fg * 8;

    f32x4 acc[4][2] = {};
    unsigned long long aw0[4], aw1[4];
    uint4 b0[2][2], b1[2][2];

#define LOADA(dst, s)                                         \
    _Pragma("unroll")                                         \
    for (int mt = 0; mt < 4; ++mt)                            \
        dst[mt] = pA[(size_t)(s) * BB + mt * 16];

#define LOADB(dst, s)                                         \
    _Pragma("unroll")                                         \
    for (int n = 0; n < 2; ++n) {                             \
        const ushort* p = pB + ((size_t)(s) * NROWS_M + n * 16) * 64; \
        dst[n][0] = *reinterpret_cast<const uint4*>(p);       \
        dst[n][1] = *reinterpret_cast<const uint4*>(p + 32);  \
    }

#define COMPUTE(aw, bf)                                       \
    _Pragma("unroll")                                         \
    for (int mt = 0; mt < 4; ++mt) {                          \
        unsigned lo = (unsigned)aw[mt];                       \
        unsigned hi = (unsigned)(aw[mt] >> 32);               \
        short8 af0 = expand8((lo >> (fg * 8)) & 0xffu);       \
        short8 af1 = expand8((hi >> (fg * 8)) & 0xffu);       \
        _Pragma("unroll")                                     \
        for (int n = 0; n < 2; ++n) {                         \
            acc[mt][n] = __builtin_amdgcn_mfma_f32_16x16x32_bf16( \
                af0, __builtin_bit_cast(short8, bf[n][0]), acc[mt][n], 0, 0, 0); \
            acc[mt][n] = __builtin_amdgcn_mfma_f32_16x16x32_bf16( \
                af1, __builtin_bit_cast(short8, bf[n][1]), acc[mt][n], 0, 0, 0); \
        }                                                     \
    }

    LOADA(aw0, 0)
    LOADB(b0, 0)

    for (int s = 0; s < STEPS; s += 2) {
        LOADA(aw1, s + 1)
        LOADB(b1, s + 1)
        COMPUTE(aw0, b0)
        if (s + 2 < STEPS) {
            LOADA(aw0, s + 2)
            LOADB(b0, s + 2)
        }
        COMPUTE(aw1, b1)
    }

    #pragma unroll
    for (int mt = 0; mt < 4; ++mt)
        #pragma unroll
        for (int n = 0; n < 2; ++n)
            #pragma unroll
            for (int r = 0; r < 4; ++r) {
                int grow = row0 + mt * 16 + fg * 4 + r;
                int col = wcol + n * 16 + fr;
                Cpart[((size_t)seg * BB + grow) * NROWS_M + col] = acc[mt][n][r];
            }
#undef LOADA
#undef LOADB
#undef COMPUTE
}

// ---------------- K3: popcount-sim + reduce + softmax + combine -----------
__global__ __launch_bounds__(256) void k3_final(
        const unsigned long long* __restrict__ packedT,
        const unsigned long long* __restrict__ cpackT,
        const float* __restrict__ Cpart, float* __restrict__ res) {
    const int tid = threadIdx.x;
    const int lane = tid & 63;                 // model index
    const int wv = __builtin_amdgcn_readfirstlane(tid >> 6);
    const int row = blockIdx.x * 4 + wv;

    // sim via XOR+popcount (pad bits are 0 on both sides -> cancel)
    int mis = 0;
    const unsigned long long* ap = packedT + row;
    const unsigned long long* cp = cpackT + lane;
    for (int w = 0; w < NWORDS; ++w) {
        unsigned long long a = ap[(size_t)w * BB];     // wave-uniform
        unsigned long long c = cp[(size_t)w * 64];
        mis += __popcll(a ^ c);
    }
    float sim = (float)(DD - 2 * mis) * 1e-4f;

    float mh = 0.f, ml = 0.f;
    #pragma unroll
    for (int seg = 0; seg < KSPLIT; ++seg) {
        const float* base = Cpart + ((size_t)seg * BB + row) * NROWS_M;
        mh += base[lane];
        ml += base[64 + lane];
    }
    float mr = mh + ml;

    float mx = sim;
    #pragma unroll
    for (int o = 32; o; o >>= 1) mx = fmaxf(mx, __shfl_xor(mx, o, 64));
    float e = expf(sim - mx);
    float num = e * mr;
    float Z = e;
    #pragma unroll
    for (int o = 32; o; o >>= 1) {
        Z += __shfl_xor(Z, o, 64);
        num += __shfl_xor(num, o, 64);
    }
    if (lane == 0) res[row] = num / Z;
}

extern "C" void kernel_launch(void* const* d_in, const int* in_sizes, int n_in,
                              void* d_out, int out_size, void* d_ws, size_t ws_size,
                              hipStream_t stream) {
    const float* x = (const float*)d_in[0];
    const float* W = (const float*)d_in[1];
    const float* bias = (const float*)d_in[2];
    const float* M = (const float*)d_in[3];
    const float* cluster = (const float*)d_in[4];

    float* res = (float*)d_out;            // [4096]
    float* enc = (float*)d_out + BB;       // [4096][10000]

    ushort* Bk = (ushort*)((char*)d_ws + WS_BK_OFF);
    unsigned long long* cpackT = (unsigned long long*)((char*)d_ws + WS_CPK_OFF);
    unsigned long long* packedT = (unsigned long long*)((char*)d_ws + WS_PACK_OFF);
    float* Cpart = (float*)((char*)d_ws + WS_CPART_OFF);

    k0_build_B<<<dim3(40, NROWS_M), 256, 0, stream>>>(M, Bk);
    k0b_pack_c<<<40, 256, 0, stream>>>(cluster, cpackT);
    k1_enc<<<dim3(40, 64), 256, 0, stream>>>(x, W, bias, enc, packedT);
    k2_gemm<<<dim3(64, KSPLIT), 256, 0, stream>>>(packedT, Bk, Cpart);
    k3_final<<<BB / 4, 256, 0, stream>>>(packedT, cpackT, Cpart, res);
}

// Round 16
// 165.627 us; speedup vs baseline: 1.2804x; 1.2804x over previous
//
#include <hip/hip_runtime.h>
#include <hip/hip_bf16.h>

#define BB 4096
#define SZ 32
#define DD 10000
#define DPAD 10240
#define NMOD 64
#define NROWS_M 128   // Mh(64) + Ml(64)
#define KSPLIT 4
#define KSEG 2560     // DPAD / KSPLIT
#define NWORDS 160    // DPAD/64 packed words per row
#define STEPS 40      // KSEG/64

// ws layout (bytes)
#define WS_BK_OFF     0u                 // 160*128*64*2 = 2.62 MB
#define WS_CPK_OFF    3145728u           // 160*64*8 = 80 KB
#define WS_PACK_OFF   4194304u           // 160*4096*8 = 5.24 MB
#define WS_CPART_OFF  10485760u          // 4*4096*128*4 = 8.39 MB  (end 18.9 MB)

typedef __attribute__((ext_vector_type(4))) float f32x4;
typedef __attribute__((ext_vector_type(8))) short short8;

static __device__ __forceinline__ ushort f2bf(float f) {
    unsigned u = __builtin_bit_cast(unsigned, f);
    unsigned r = (u + 0x7fffu + ((u >> 16) & 1u)) >> 16;   // RNE
    return (ushort)r;
}

// sign pipeline: 1 iff cosf(t+bk)*sinf(t) > 0, else 0 (covers ==0 -> -1).
static __device__ __forceinline__ int sign_pm(float t, float bk) {
    if (t == 0.0f) return 0;
    const double INV_PI_D = 0.31830988618379067153776752674503;
    float v = t + bk;
    long long n1 = (long long)floor((double)t * INV_PI_D);
    long long n2 = (long long)floor(fma((double)v, INV_PI_D, 0.5));
    return (int)(((n1 + n2) & 1LL) ^ 1LL);
}

// expand 8 packed bits (bit=1 -> +1.0bf16, 0 -> -1.0bf16) into short8
static __device__ __forceinline__ short8 expand8(unsigned b) {
    unsigned nb = ~b;
    unsigned r0 = 0x3F803F80u | ((nb & 1u) << 15) | ((nb & 2u) << 30);
    unsigned r1 = 0x3F803F80u | (((nb >> 2) & 1u) << 15) | (((nb >> 2) & 2u) << 30);
    unsigned r2 = 0x3F803F80u | (((nb >> 4) & 1u) << 15) | (((nb >> 4) & 2u) << 30);
    unsigned r3 = 0x3F803F80u | (((nb >> 6) & 1u) << 15) | (((nb >> 6) & 2u) << 30);
    uint4 u = make_uint4(r0, r1, r2, r3);
    return __builtin_bit_cast(short8, u);
}

// ---------------- K0: build Bk [160][128][64] bf16 (Mh, Ml) ---------------
__global__ __launch_bounds__(256) void k0_build_B(
        const float* __restrict__ M, ushort* __restrict__ Bk) {
    int k = blockIdx.x * 256 + threadIdx.x;   // 0..10239
    int row = blockIdx.y;                      // 0..127
    ushort u = 0;
    if (k < DD) {
        float m = M[(size_t)(row & 63) * DD + k];
        ushort mh = f2bf(m);
        if (row < 64) {
            u = mh;
        } else {
            float mhf = __builtin_bit_cast(float, (unsigned)mh << 16);
            u = f2bf(m - mhf);
        }
    }
    int step = k >> 6, kk = k & 63;
    Bk[((size_t)step * NROWS_M + row) * 64 + kk] = u;
}

// ---------------- K0b: pack cluster signs -> cpackT [160][64] u64 ---------
__global__ __launch_bounds__(256) void k0b_pack_c(
        const float* __restrict__ cluster, unsigned long long* __restrict__ cpackT) {
    const int tid = threadIdx.x;
    const int lane = tid & 63;
    const int wv = __builtin_amdgcn_readfirstlane(tid >> 6);
    const int w = blockIdx.x * 4 + wv;        // 0..159
    const int kb = w * 64;
    unsigned long long myw = 0;
    for (int m = 0; m < 64; ++m) {
        int k = kb + lane;
        int bit = (k < DD) ? (cluster[(size_t)m * DD + k] > 0.f ? 1 : 0) : 0;
        unsigned long long bal = __ballot(bit);
        if (lane == m) myw = bal;
    }
    cpackT[(size_t)w * 64 + lane] = myw;
}

// ---------------- K1: encode (T_G ordering) -------------------------------
// thread = column k (W row in 32 VGPRs, loaded once). x rows are wave-
// uniform -> SGPR s_load double-buffer (no LDS, no per-lane x traffic).
__global__ __launch_bounds__(256, 4) void k1_enc(
        const float* __restrict__ x, const float* __restrict__ W,
        const float* __restrict__ bias, float* __restrict__ enc_out,
        unsigned long long* __restrict__ packedT) {
    const int tid = threadIdx.x;
    const int k = blockIdx.x * 256 + tid;
    const bool valid = (k < DD);
    const int kw = valid ? k : 0;
    const int lane = tid & 63;
    const int colg = blockIdx.x * 4 + (tid >> 6);   // packed word 0..159
    const int i0 = blockIdx.y * 64;

    float4 w4[8];
    {
        const float4* wg = reinterpret_cast<const float4*>(W) + (size_t)kw * 8;
        #pragma unroll
        for (int q = 0; q < 8; ++q) w4[q] = wg[q];
    }
    const float bk = bias[kw];

    // wave-uniform x base for this row-block (8 float4 per row)
    const float4* xb4 = reinterpret_cast<const float4*>(x + (size_t)i0 * SZ);

    float4 xa[8], xb[8];
    #pragma unroll
    for (int q = 0; q < 8; ++q) xa[q] = xb4[q];     // row 0

    auto dorow = [&](int i, const float4* xr) {
        float g0 = 0.f, g1 = 0.f, g2 = 0.f, g3 = 0.f;
        #pragma unroll
        for (int q = 0; q < 8; ++q) {
            g0 = fmaf(w4[q].x, xr[q].x, g0);
            g1 = fmaf(w4[q].y, xr[q].y, g1);
            g2 = fmaf(w4[q].z, xr[q].z, g2);
            g3 = fmaf(w4[q].w, xr[q].w, g3);
        }
        float t = (g0 + g1) + (g2 + g3);
        int e = valid ? sign_pm(t, bk) : 0;
        unsigned long long bal = __ballot(e);
        if (lane == 0) packedT[(size_t)colg * BB + (i0 + i)] = bal;
        if (valid) enc_out[(size_t)(i0 + i) * DD + k] = e ? 1.f : -1.f;
    };

    for (int i = 0; i < 64; i += 2) {
        #pragma unroll
        for (int q = 0; q < 8; ++q) xb[q] = xb4[(i + 1) * 8 + q];
        dorow(i, xa);
        if (i + 2 < 64) {
            #pragma unroll
            for (int q = 0; q < 8; ++q) xa[q] = xb4[(i + 2) * 8 + q];
        }
        dorow(i + 1, xb);
    }
}

// ---------------- K2: fragment-direct MFMA GEMM, M-part only --------------
// grid (64 row-groups, 4 segs), 256 thr = 4 waves = 4 col-groups of 32.
__global__ __launch_bounds__(256, 2) void k2_gemm(
        const unsigned long long* __restrict__ packedT,  // [160][4096]
        const ushort* __restrict__ Bk,                   // [160][128][64]
        float* __restrict__ Cpart) {
    const int tid = threadIdx.x;
    const int wid = tid >> 6;       // col-group 0..3
    const int lane = tid & 63;
    const int fr = lane & 15;
    const int fg = lane >> 4;

    const int row0 = blockIdx.x * 64;
    const int seg = blockIdx.y;
    const int wcol = wid * 32;

    const unsigned long long* pA = packedT + (size_t)(seg * STEPS) * BB + row0 + fr;
    const ushort* pB = Bk + ((size_t)(seg * STEPS) * NROWS_M + wcol + fr) * 64 + fg * 8;

    f32x4 acc[4][2] = {};
    unsigned long long aw0[4], aw1[4];
    uint4 b0[2][2], b1[2][2];

#define LOADA(dst, s)                                         \
    _Pragma("unroll")                                         \
    for (int mt = 0; mt < 4; ++mt)                            \
        dst[mt] = pA[(size_t)(s) * BB + mt * 16];

#define LOADB(dst, s)                                         \
    _Pragma("unroll")                                         \
    for (int n = 0; n < 2; ++n) {                             \
        const ushort* p = pB + ((size_t)(s) * NROWS_M + n * 16) * 64; \
        dst[n][0] = *reinterpret_cast<const uint4*>(p);       \
        dst[n][1] = *reinterpret_cast<const uint4*>(p + 32);  \
    }

#define COMPUTE(aw, bf)                                       \
    _Pragma("unroll")                                         \
    for (int mt = 0; mt < 4; ++mt) {                          \
        unsigned lo = (unsigned)aw[mt];                       \
        unsigned hi = (unsigned)(aw[mt] >> 32);               \
        short8 af0 = expand8((lo >> (fg * 8)) & 0xffu);       \
        short8 af1 = expand8((hi >> (fg * 8)) & 0xffu);       \
        _Pragma("unroll")                                     \
        for (int n = 0; n < 2; ++n) {                         \
            acc[mt][n] = __builtin_amdgcn_mfma_f32_16x16x32_bf16( \
                af0, __builtin_bit_cast(short8, bf[n][0]), acc[mt][n], 0, 0, 0); \
            acc[mt][n] = __builtin_amdgcn_mfma_f32_16x16x32_bf16( \
                af1, __builtin_bit_cast(short8, bf[n][1]), acc[mt][n], 0, 0, 0); \
        }                                                     \
    }

    LOADA(aw0, 0)
    LOADB(b0, 0)

    for (int s = 0; s < STEPS; s += 2) {
        LOADA(aw1, s + 1)
        LOADB(b1, s + 1)
        COMPUTE(aw0, b0)
        if (s + 2 < STEPS) {
            LOADA(aw0, s + 2)
            LOADB(b0, s + 2)
        }
        COMPUTE(aw1, b1)
    }

    #pragma unroll
    for (int mt = 0; mt < 4; ++mt)
        #pragma unroll
        for (int n = 0; n < 2; ++n)
            #pragma unroll
            for (int r = 0; r < 4; ++r) {
                int grow = row0 + mt * 16 + fg * 4 + r;
                int col = wcol + n * 16 + fr;
                Cpart[((size_t)seg * BB + grow) * NROWS_M + col] = acc[mt][n][r];
            }
#undef LOADA
#undef LOADB
#undef COMPUTE
}

// ---------------- K3: popcount-sim + reduce + softmax + combine -----------
__global__ __launch_bounds__(256) void k3_final(
        const unsigned long long* __restrict__ packedT,
        const unsigned long long* __restrict__ cpackT,
        const float* __restrict__ Cpart, float* __restrict__ res) {
    const int tid = threadIdx.x;
    const int lane = tid & 63;                 // model index
    const int wv = __builtin_amdgcn_readfirstlane(tid >> 6);
    const int row = blockIdx.x * 4 + wv;

    // sim via XOR+popcount (pad bits are 0 on both sides -> cancel)
    int mis = 0;
    const unsigned long long* ap = packedT + row;
    const unsigned long long* cp = cpackT + lane;
    for (int w = 0; w < NWORDS; ++w) {
        unsigned long long a = ap[(size_t)w * BB];     // wave-uniform
        unsigned long long c = cp[(size_t)w * 64];
        mis += __popcll(a ^ c);
    }
    float sim = (float)(DD - 2 * mis) * 1e-4f;

    float mh = 0.f, ml = 0.f;
    #pragma unroll
    for (int seg = 0; seg < KSPLIT; ++seg) {
        const float* base = Cpart + ((size_t)seg * BB + row) * NROWS_M;
        mh += base[lane];
        ml += base[64 + lane];
    }
    float mr = mh + ml;

    float mx = sim;
    #pragma unroll
    for (int o = 32; o; o >>= 1) mx = fmaxf(mx, __shfl_xor(mx, o, 64));
    float e = expf(sim - mx);
    float num = e * mr;
    float Z = e;
    #pragma unroll
    for (int o = 32; o; o >>= 1) {
        Z += __shfl_xor(Z, o, 64);
        num += __shfl_xor(num, o, 64);
    }
    if (lane == 0) res[row] = num / Z;
}

extern "C" void kernel_launch(void* const* d_in, const int* in_sizes, int n_in,
                              void* d_out, int out_size, void* d_ws, size_t ws_size,
                              hipStream_t stream) {
    const float* x = (const float*)d_in[0];
    const float* W = (const float*)d_in[1];
    const float* bias = (const float*)d_in[2];
    const float* M = (const float*)d_in[3];
    const float* cluster = (const float*)d_in[4];

    float* res = (float*)d_out;            // [4096]
    float* enc = (float*)d_out + BB;       // [4096][10000]

    ushort* Bk = (ushort*)((char*)d_ws + WS_BK_OFF);
    unsigned long long* cpackT = (unsigned long long*)((char*)d_ws + WS_CPK_OFF);
    unsigned long long* packedT = (unsigned long long*)((char*)d_ws + WS_PACK_OFF);
    float* Cpart = (float*)((char*)d_ws + WS_CPART_OFF);

    k0_build_B<<<dim3(40, NROWS_M), 256, 0, stream>>>(M, Bk);
    k0b_pack_c<<<40, 256, 0, stream>>>(cluster, cpackT);
    k1_enc<<<dim3(40, 64), 256, 0, stream>>>(x, W, bias, enc, packedT);
    k2_gemm<<<dim3(64, KSPLIT), 256, 0, stream>>>(packedT, Bk, Cpart);
    k3_final<<<BB / 4, 256, 0, stream>>>(packedT, cpackT, Cpart, res);
}

// Round 17
// 157.712 us; speedup vs baseline: 1.3447x; 1.0502x over previous
//
#include <hip/hip_runtime.h>
#include <hip/hip_bf16.h>

#define BB 4096
#define SZ 32
#define DD 10000
#define DPAD 10240
#define NMOD 64
#define NROWS_B 192   // cluster(64) + Mh(64) + Ml(64)
#define KSPLIT 4
#define KSEG 2560     // DPAD / KSPLIT
#define NWORDS 160    // DPAD/64 packed words per row
#define STEPS 40      // KSEG/64

// ws layout (bytes) — identical footprint to round 12 (proven)
#define WS_BK_OFF     0u                 // 160*192*64*2 = 3.93 MB
#define WS_PACK_OFF   (4u << 20)         // 160*4096*8 = 5.24 MB
#define WS_CPART_OFF  9437184u           // 4*4096*192*4 = 12.6 MB (end 22.0 MB)

typedef __attribute__((ext_vector_type(4))) float f32x4;
typedef __attribute__((ext_vector_type(8))) short short8;

static __device__ __forceinline__ ushort f2bf(float f) {
    unsigned u = __builtin_bit_cast(unsigned, f);
    unsigned r = (u + 0x7fffu + ((u >> 16) & 1u)) >> 16;   // RNE
    return (ushort)r;
}

// sign pipeline: 1 iff cosf(t+bk)*sinf(t) > 0, else 0 (covers ==0 -> -1).
static __device__ __forceinline__ int sign_pm(float t, float bk) {
    if (t == 0.0f) return 0;
    const double INV_PI_D = 0.31830988618379067153776752674503;
    float v = t + bk;
    long long n1 = (long long)floor((double)t * INV_PI_D);
    long long n2 = (long long)floor(fma((double)v, INV_PI_D, 0.5));
    return (int)(((n1 + n2) & 1LL) ^ 1LL);
}

// expand 8 packed bits (bit=1 -> +1.0bf16, 0 -> -1.0bf16) into short8
static __device__ __forceinline__ short8 expand8(unsigned b) {
    unsigned nb = ~b;
    unsigned r0 = 0x3F803F80u | ((nb & 1u) << 15) | ((nb & 2u) << 30);
    unsigned r1 = 0x3F803F80u | (((nb >> 2) & 1u) << 15) | (((nb >> 2) & 2u) << 30);
    unsigned r2 = 0x3F803F80u | (((nb >> 4) & 1u) << 15) | (((nb >> 4) & 2u) << 30);
    unsigned r3 = 0x3F803F80u | (((nb >> 6) & 1u) << 15) | (((nb >> 6) & 2u) << 30);
    uint4 u = make_uint4(r0, r1, r2, r3);
    return __builtin_bit_cast(short8, u);
}

// ---------------- K0: build Bk [160][192][64] bf16 (cluster, Mh, Ml) ------
__global__ __launch_bounds__(256) void k0_build_B(
        const float* __restrict__ M, const float* __restrict__ cluster,
        ushort* __restrict__ Bk) {
    int k = blockIdx.x * 256 + threadIdx.x;   // 0..10239
    int row = blockIdx.y;                      // 0..191
    ushort u = 0;
    if (k < DD) {
        if (row < 64) {
            u = f2bf(cluster[(size_t)row * DD + k]);
        } else {
            float m = M[(size_t)(row & 63) * DD + k];
            ushort mh = f2bf(m);
            if (row < 128) {
                u = mh;
            } else {
                float mhf = __builtin_bit_cast(float, (unsigned)mh << 16);
                u = f2bf(m - mhf);
            }
        }
    }
    int step = k >> 6, kk = k & 63;
    Bk[((size_t)step * NROWS_B + row) * 64 + kk] = u;
}

// ---------------- K1: encode (T_G ordering) -------------------------------
// thread = column k; W row pinned in 32 VGPRs (asm barrier prevents
// rematerialization); x rows wave-uniform -> SGPR s_load double-buffer.
__global__ __launch_bounds__(256, 4) void k1_enc(
        const float* __restrict__ x, const float* __restrict__ W,
        const float* __restrict__ bias, float* __restrict__ enc_out,
        unsigned long long* __restrict__ packedT) {
    const int tid = threadIdx.x;
    const int k = blockIdx.x * 256 + tid;
    const bool valid = (k < DD);
    const int kw = valid ? k : 0;
    const int lane = tid & 63;
    const int colg = blockIdx.x * 4 + (tid >> 6);   // packed word 0..159
    const int i0 = blockIdx.y * 64;

    float4 w4[8];
    {
        const float4* wg = reinterpret_cast<const float4*>(W) + (size_t)kw * 8;
        #pragma unroll
        for (int q = 0; q < 8; ++q) w4[q] = wg[q];
    }
    const float bk = bias[kw];
    // pin W fragment into VGPRs — compiler cannot re-load it per row
    #pragma unroll
    for (int q = 0; q < 8; ++q)
        asm volatile("" : "+v"(w4[q].x), "+v"(w4[q].y), "+v"(w4[q].z), "+v"(w4[q].w));

    const float4* xb4 = reinterpret_cast<const float4*>(x + (size_t)i0 * SZ);

    float4 xa[8], xb[8];
    #pragma unroll
    for (int q = 0; q < 8; ++q) xa[q] = xb4[q];     // row 0

    auto dorow = [&](int i, const float4* xr) {
        float g0 = 0.f, g1 = 0.f, g2 = 0.f, g3 = 0.f;
        #pragma unroll
        for (int q = 0; q < 8; ++q) {
            g0 = fmaf(w4[q].x, xr[q].x, g0);
            g1 = fmaf(w4[q].y, xr[q].y, g1);
            g2 = fmaf(w4[q].z, xr[q].z, g2);
            g3 = fmaf(w4[q].w, xr[q].w, g3);
        }
        float t = (g0 + g1) + (g2 + g3);
        int e = valid ? sign_pm(t, bk) : 0;
        unsigned long long bal = __ballot(e);
        if (lane == 0) packedT[(size_t)colg * BB + (i0 + i)] = bal;
        if (valid) enc_out[(size_t)(i0 + i) * DD + k] = e ? 1.f : -1.f;
    };

    for (int i = 0; i < 64; i += 2) {
        #pragma unroll
        for (int q = 0; q < 8; ++q) xb[q] = xb4[(i + 1) * 8 + q];
        dorow(i, xa);
        if (i + 2 < 64) {
            #pragma unroll
            for (int q = 0; q < 8; ++q) xa[q] = xb4[(i + 2) * 8 + q];
        }
        dorow(i + 1, xb);
    }
}

// ---------------- K2: fragment-direct MFMA GEMM (no LDS, no barriers) -----
// grid (128 row-groups of 32, 4 segs) = 512 blocks (2/CU), 256 thr = 4 waves
// = 4 col-groups of 48 cols (cluster + Mh + Ml all via MFMA).
__global__ __launch_bounds__(256, 2) void k2_gemm(
        const unsigned long long* __restrict__ packedT,  // [160][4096]
        const ushort* __restrict__ Bk,                   // [160][192][64]
        float* __restrict__ Cpart) {
    const int tid = threadIdx.x;
    const int wid = tid >> 6;       // col-group 0..3
    const int lane = tid & 63;
    const int fr = lane & 15;
    const int fg = lane >> 4;

    const int row0 = blockIdx.x * 32;
    const int seg = blockIdx.y;
    const int wcol = wid * 48;

    const unsigned long long* pA = packedT + (size_t)(seg * STEPS) * BB + row0 + fr;
    const ushort* pB = Bk + ((size_t)(seg * STEPS) * NROWS_B + wcol + fr) * 64 + fg * 8;

    f32x4 acc[2][3] = {};
    unsigned long long aw0[2], aw1[2];
    uint4 b0[3][2], b1[3][2];

#define LOADA(dst, s)                                         \
    _Pragma("unroll")                                         \
    for (int mt = 0; mt < 2; ++mt)                            \
        dst[mt] = pA[(size_t)(s) * BB + mt * 16];

#define LOADB(dst, s)                                         \
    _Pragma("unroll")                                         \
    for (int n = 0; n < 3; ++n) {                             \
        const ushort* p = pB + ((size_t)(s) * NROWS_B + n * 16) * 64; \
        dst[n][0] = *reinterpret_cast<const uint4*>(p);       \
        dst[n][1] = *reinterpret_cast<const uint4*>(p + 32);  \
    }

#define COMPUTE(aw, bf)                                       \
    _Pragma("unroll")                                         \
    for (int mt = 0; mt < 2; ++mt) {                          \
        unsigned lo = (unsigned)aw[mt];                       \
        unsigned hi = (unsigned)(aw[mt] >> 32);               \
        short8 af0 = expand8((lo >> (fg * 8)) & 0xffu);       \
        short8 af1 = expand8((hi >> (fg * 8)) & 0xffu);       \
        _Pragma("unroll")                                     \
        for (int n = 0; n < 3; ++n) {                         \
            acc[mt][n] = __builtin_amdgcn_mfma_f32_16x16x32_bf16( \
                af0, __builtin_bit_cast(short8, bf[n][0]), acc[mt][n], 0, 0, 0); \
            acc[mt][n] = __builtin_amdgcn_mfma_f32_16x16x32_bf16( \
                af1, __builtin_bit_cast(short8, bf[n][1]), acc[mt][n], 0, 0, 0); \
        }                                                     \
    }

    LOADA(aw0, 0)
    LOADB(b0, 0)

    for (int s = 0; s < STEPS; s += 2) {
        LOADA(aw1, s + 1)
        LOADB(b1, s + 1)
        COMPUTE(aw0, b0)
        if (s + 2 < STEPS) {
            LOADA(aw0, s + 2)
            LOADB(b0, s + 2)
        }
        COMPUTE(aw1, b1)
    }

    #pragma unroll
    for (int mt = 0; mt < 2; ++mt)
        #pragma unroll
        for (int n = 0; n < 3; ++n)
            #pragma unroll
            for (int r = 0; r < 4; ++r) {
                int grow = row0 + mt * 16 + fg * 4 + r;
                int col = wcol + n * 16 + fr;
                Cpart[((size_t)seg * BB + grow) * NROWS_B + col] = acc[mt][n][r];
            }
#undef LOADA
#undef LOADB
#undef COMPUTE
}

// ---------------- K3: reduce partials + softmax + combine ----------------
__global__ __launch_bounds__(256) void k3_final(
        const float* __restrict__ Cpart, float* __restrict__ res) {
    const int wid = threadIdx.x >> 6;
    const int lane = threadIdx.x & 63;
    const int row = blockIdx.x * 4 + wid;

    float s = 0.f, mh = 0.f, ml = 0.f;
    #pragma unroll
    for (int seg = 0; seg < KSPLIT; ++seg) {
        const float* base = Cpart + ((size_t)seg * BB + row) * NROWS_B;
        s += base[lane];
        mh += base[64 + lane];
        ml += base[128 + lane];
    }
    float sim = s * 1e-4f;          // exact norms: 100 * 100
    float mr = mh + ml;

    float mx = sim;
    #pragma unroll
    for (int o = 32; o; o >>= 1) mx = fmaxf(mx, __shfl_xor(mx, o, 64));
    float e = expf(sim - mx);
    float num = e * mr;
    float Z = e;
    #pragma unroll
    for (int o = 32; o; o >>= 1) {
        Z += __shfl_xor(Z, o, 64);
        num += __shfl_xor(num, o, 64);
    }
    if (lane == 0) res[row] = num / Z;
}

extern "C" void kernel_launch(void* const* d_in, const int* in_sizes, int n_in,
                              void* d_out, int out_size, void* d_ws, size_t ws_size,
                              hipStream_t stream) {
    const float* x = (const float*)d_in[0];
    const float* W = (const float*)d_in[1];
    const float* bias = (const float*)d_in[2];
    const float* M = (const float*)d_in[3];
    const float* cluster = (const float*)d_in[4];

    float* res = (float*)d_out;            // [4096]
    float* enc = (float*)d_out + BB;       // [4096][10000]

    ushort* Bk = (ushort*)((char*)d_ws + WS_BK_OFF);
    unsigned long long* packedT = (unsigned long long*)((char*)d_ws + WS_PACK_OFF);
    float* Cpart = (float*)((char*)d_ws + WS_CPART_OFF);

    k0_build_B<<<dim3(40, NROWS_B), 256, 0, stream>>>(M, cluster, Bk);
    k1_enc<<<dim3(40, 64), 256, 0, stream>>>(x, W, bias, enc, packedT);
    k2_gemm<<<dim3(128, KSPLIT), 256, 0, stream>>>(packedT, Bk, Cpart);
    k3_final<<<BB / 4, 256, 0, stream>>>(Cpart, res);
}